// Round 5
// baseline (735.834 us; speedup 1.0000x reference)
//
#include <hip/hip_runtime.h>

// LightGCN: out = (x0 + A x0 + A^2 x0 + A^3 x0) / 4, COO 4M nnz, N=300k, D=64.
// R5: inter-layer activations bf16 (row=128B); R6: SGPR edge records.
// R7: hist/scan kernels folded into bucket pipeline (bhist/bscan/bucketB).
// R8: fp32 acc deleted; mean fused into final layer; layers 1-2 write-only.
// R9: spmm inner loop restructured for memory-level parallelism. Evidence:
//     dur invariant to FETCH (292..345MB all ~160us), VALU 21% -> latency-
//     bound on the serial [s_load -> wait -> 4 gathers -> wait] chain
//     (~200cyc/edge, only 4 outstanding gathers/wave). Now: 16-edge chunks,
//     records as one contiguous scalar block (packed has a 16-record zero
//     pad so no clamp; overread records belong to the next rows -> their
//     gathers are useful L1/L2 prefetch), 16 gathers issued back-to-back,
//     out-of-row values zeroed via wave-uniform s_cselect (SALU only).
// R10: identical resubmission of R9 (previous bench aborted with an
//     infra-side "container failed twice"; source audit found no OOB/
//     capture-rule defect, so re-measure before changing anything).

#define NUSERS 200000
#define NITEMS 100000
#define NNODES 300000
#define DIM 64
#define NNZ_CNT 4000000

#define BSHIFT 10
#define BROWS  (1 << BSHIFT)                               // 1024 rows per bucket
#define NB     ((NNODES + BROWS - 1) >> BSHIFT)            // 293 buckets
#define EPB    8192                                        // edges per block (hist/A)

// ---------------- bf16 helpers (RNE) ----------------

__device__ __forceinline__ unsigned short f32_to_bf16(float f) {
    unsigned u = __float_as_uint(f);
    u += 0x7FFFu + ((u >> 16) & 1u);
    return (unsigned short)(u >> 16);
}
__device__ __forceinline__ float bf16_to_f32(unsigned short h) {
    return __uint_as_float(((unsigned)h) << 16);
}

// ---------------- bucket totals: LDS hist, few global atomics ----------------

__global__ void __launch_bounds__(256) k_bhist(const int* __restrict__ rows,
                                               int* __restrict__ bcnt) {
    __shared__ int hist[NB];
    int t = threadIdx.x;
    int e0 = blockIdx.x * EPB;
    for (int i = t; i < NB; i += 256) hist[i] = 0;
    __syncthreads();
    for (int k = 0; k < EPB / 256; ++k) {
        int e = e0 + k * 256 + t;
        if (e < NNZ_CNT) atomicAdd(&hist[rows[e] >> BSHIFT], 1);
    }
    __syncthreads();
    for (int i = t; i < NB; i += 256) {
        int h = hist[i];
        if (h) atomicAdd(&bcnt[i], h);
    }
}

// 1 block, 512 threads: exclusive scan of bucket counts -> bases + cursors.
__global__ void k_bscan(const int* __restrict__ bcnt, int* __restrict__ bbase,
                        int* __restrict__ gcur) {
    int t = threadIdx.x;
    int v = (t < NB) ? bcnt[t] : 0;
    __shared__ int lds[512];
    lds[t] = v; __syncthreads();
    for (int d = 1; d < 512; d <<= 1) {
        int cur = lds[t];
        int add = (t >= d) ? lds[t - d] : 0;
        __syncthreads();
        lds[t] = cur + add;
        __syncthreads();
    }
    if (t < NB) {
        int e = lds[t] - v;          // exclusive
        bbase[t] = e;
        gcur[t]  = e;
    }
    if (t == 511) bbase[NB] = lds[511];   // == NNZ
}

// ---------------- Phase A: bucket staging (LDS-binned) ----------------

__global__ void __launch_bounds__(256) k_bucketA(
        const int* __restrict__ rows, const int* __restrict__ cols,
        const float* __restrict__ vals, int* __restrict__ gcursor,
        int2* __restrict__ staged) {
    __shared__ int hist[NB];
    __shared__ int lbase[NB];
    __shared__ int lcur[NB];
    int t = threadIdx.x;
    int e0 = blockIdx.x * EPB;
    for (int i = t; i < NB; i += 256) { hist[i] = 0; lcur[i] = 0; }
    __syncthreads();
    // pass 1: local histogram
    for (int k = 0; k < EPB / 256; ++k) {
        int e = e0 + k * 256 + t;
        if (e < NNZ_CNT) atomicAdd(&hist[rows[e] >> BSHIFT], 1);
    }
    __syncthreads();
    // reserve contiguous ranges per bucket
    for (int i = t; i < NB; i += 256) {
        int h = hist[i];
        lbase[i] = h ? atomicAdd(&gcursor[i], h) : 0;
    }
    __syncthreads();
    // pass 2: place edges
    for (int k = 0; k < EPB / 256; ++k) {
        int e = e0 + k * 256 + t;
        if (e >= NNZ_CNT) continue;
        int r = rows[e];
        int b = r >> BSHIFT;
        int p = lbase[b] + atomicAdd(&lcur[b], 1);
        int2 rec;
        rec.x = ((r & (BROWS - 1)) << 19) | cols[e];   // rel_row[10] | col[19]
        rec.y = __float_as_int(vals[e]);
        staged[p] = rec;
    }
}

// ---------------- Phase B: per-bucket count + scan + row sort ----------------

__global__ void __launch_bounds__(1024) k_bucketB(
        const int* __restrict__ bbase, const int2* __restrict__ staged,
        int2* __restrict__ packed, int* __restrict__ rowptr) {
    __shared__ int rcnt[BROWS];
    __shared__ int cur[BROWS];
    int b = blockIdx.x;
    int t = threadIdx.x;
    int r0 = b << BSHIFT;
    int r1 = min(r0 + BROWS, NNODES);
    int nrows = r1 - r0;
    rcnt[t] = 0;
    __syncthreads();
    int start = bbase[b];
    int end   = bbase[b + 1];
    // pass 1: per-row counts (load only .x of each record)
    const int* sx = (const int*)staged;
    for (int idx = start + t; idx < end; idx += 1024)
        atomicAdd(&rcnt[((unsigned)sx[idx << 1]) >> 19], 1);
    __syncthreads();
    int v = rcnt[t];
    // in-place inclusive scan (Hillis-Steele)
    for (int d = 1; d < 1024; d <<= 1) {
        int c = rcnt[t];
        int a = (t >= d) ? rcnt[t - d] : 0;
        __syncthreads();
        rcnt[t] = c + a;
        __syncthreads();
    }
    int excl = rcnt[t] - v;
    cur[t] = start + excl;
    if (t < nrows) rowptr[r0 + t] = start + excl;
    if (b == NB - 1 && t == 0) rowptr[NNODES] = end;   // == NNZ
    __syncthreads();
    // pass 2: scatter to row-major packed
    for (int idx = start + t; idx < end; idx += 1024) {
        int2 rec = staged[idx];
        int rel = ((unsigned)rec.x) >> 19;
        int col = rec.x & 0x7FFFF;
        int pos = atomicAdd(&cur[rel], 1);
        int2 out; out.x = col; out.y = rec.y;
        packed[pos] = out;
    }
}

// ---------------- x0 -> bf16 ----------------

__global__ void k_init0(const float* __restrict__ ue, const float* __restrict__ ie,
                        unsigned short* __restrict__ xb0) {
    int i = blockIdx.x * blockDim.x + threadIdx.x;      // float4 index
    const int total = NNODES * DIM / 4;
    if (i >= total) return;
    const int userEnd = NUSERS * DIM / 4;
    float4 v = (i < userEnd) ? ((const float4*)ue)[i]
                             : ((const float4*)ie)[i - userEnd];
    ushort4 h;
    h.x = f32_to_bf16(v.x); h.y = f32_to_bf16(v.y);
    h.z = f32_to_bf16(v.z); h.w = f32_to_bf16(v.w);
    ((ushort4*)xb0)[i] = h;
}

// ---------------- CSR SpMM: one wave/row, 16-deep batched gathers ----------------

// Per 16-edge chunk: records loaded as one contiguous scalar block (packed is
// padded by 16 zero records, so no clamp; overread = next rows' records =
// useful prefetch), then 16 gathers issued back-to-back (16 outstanding vs 4),
// out-of-row values zeroed with wave-uniform selects (SALU, free).
// FINAL=0: y = bf16(s)                      (layers 1,2 -- write-only epilogue)
// FINAL=1: out = (x0 + x1 + x2 + s) * 0.25
template <int FINAL>
__global__ void __launch_bounds__(256) k_spmm(
        const int* __restrict__ rowptr, const int2* __restrict__ packed,
        const unsigned short* __restrict__ xin,
        unsigned short* __restrict__ y,
        const unsigned short* __restrict__ xprev,
        const float* __restrict__ ue, const float* __restrict__ ie,
        float* __restrict__ out) {
    int row  = blockIdx.x * (blockDim.x >> 6) + (threadIdx.x >> 6);
    int lane = threadIdx.x & 63;
    if (row >= NNODES) return;
    int start = __builtin_amdgcn_readfirstlane(rowptr[row]);
    int end   = __builtin_amdgcn_readfirstlane(rowptr[row + 1]);
    const unsigned short* __restrict__ xl = xin + lane;
    float s0 = 0.f, s1 = 0.f, s2 = 0.f, s3 = 0.f;
    for (int base = start; base < end; base += 16) {
        int2 e[16];
        #pragma unroll
        for (int j = 0; j < 16; ++j) e[j] = packed[base + j];   // contiguous s_load block
        float g[16];
        #pragma unroll
        for (int j = 0; j < 16; ++j)                            // 16 gathers in flight
            g[j] = bf16_to_f32(xl[(size_t)e[j].x << 6]);
        #pragma unroll
        for (int j = 0; j < 16; ++j) {
            float v = (base + j < end) ? __int_as_float(e[j].y) : 0.0f;  // uniform -> s_cselect
            float p = v * g[j];
            if ((j & 3) == 0) s0 += p;
            else if ((j & 3) == 1) s1 += p;
            else if ((j & 3) == 2) s2 += p;
            else s3 += p;
        }
    }
    float s = (s0 + s1) + (s2 + s3);
    size_t o = ((size_t)row << 6) + lane;
    if (FINAL) {
        float x0 = (row < NUSERS) ? ue[o] : ie[o - (size_t)NUSERS * DIM];
        float x1 = bf16_to_f32(xprev[o]);
        float x2 = bf16_to_f32(xin[o]);
        out[o] = (x0 + x1 + x2 + s) * 0.25f;
    } else {
        y[o] = f32_to_bf16(s);
    }
}

// ---------------- launch ----------------

extern "C" void kernel_launch(void* const* d_in, const int* in_sizes, int n_in,
                              void* d_out, int out_size, void* d_ws, size_t ws_size,
                              hipStream_t stream) {
    const float* ue   = (const float*)d_in[0];
    const float* ie   = (const float*)d_in[1];
    const int*   rows = (const int*)d_in[2];
    const int*   cols = (const int*)d_in[3];
    const float* vals = (const float*)d_in[4];
    float* out = (float*)d_out;

    const size_t embN = (size_t)NNODES * DIM;            // 19.2M elements
    char* p = (char*)d_ws;
    unsigned short* xb0 = (unsigned short*)p;  p += embN * 2;                 // 38.4 MB
    unsigned short* xb1 = (unsigned short*)p;  p += embN * 2;                 // 38.4 MB
    unsigned short* xb2 = (unsigned short*)p;  p += embN * 2;                 // 38.4 MB
    int*   rowptr = (int*)p;              p += (size_t)(NNODES + 16) * 4;     // 1.2 MB
    int*   bcnt   = (int*)p;              p += 512 * 4;
    int*   bbase  = (int*)p;              p += 512 * 4;
    int*   gcur   = (int*)p;              p += 512 * 4;
    int2*  staged = (int2*)p;             p += (size_t)NNZ_CNT * 8;           // 32 MB
    int2*  packed = (int2*)p;             p += (size_t)(NNZ_CNT + 16) * 8;    // 32 MB + pad

    const int row_blocks  = (NNODES + 3) / 4;             // 4 waves/block
    const int edge_hblocks = (NNZ_CNT + EPB - 1) / EPB;   // 489
    const int vec_blocks = (NNODES * DIM / 4 + 255) / 256;

    // --- bucket totals + bases ---
    hipMemsetAsync(bcnt, 0, 512 * 4, stream);
    hipMemsetAsync(packed + NNZ_CNT, 0, 16 * sizeof(int2), stream);  // gather pad
    k_bhist<<<edge_hblocks, 256, 0, stream>>>(rows, bcnt);
    k_bscan<<<1, 512, 0, stream>>>(bcnt, bbase, gcur);

    // --- bucket sort: COO -> staged (bucket-major) -> packed (row-major) ---
    k_bucketA<<<edge_hblocks, 256, 0, stream>>>(rows, cols, vals, gcur, staged);
    k_bucketB<<<NB, 1024, 0, stream>>>(bbase, staged, packed, rowptr);

    // --- x0 -> bf16 ---
    k_init0<<<vec_blocks, 256, 0, stream>>>(ue, ie, xb0);

    // --- 3 layers; mean fused into the last (reads x0 fp32 + x1,x2 bf16) ---
    k_spmm<0><<<row_blocks, 256, 0, stream>>>(rowptr, packed, xb0, xb1,
                                              (const unsigned short*)nullptr, ue, ie, (float*)nullptr);
    k_spmm<0><<<row_blocks, 256, 0, stream>>>(rowptr, packed, xb1, xb2,
                                              (const unsigned short*)nullptr, ue, ie, (float*)nullptr);
    k_spmm<1><<<row_blocks, 256, 0, stream>>>(rowptr, packed, xb2, (unsigned short*)nullptr,
                                              xb1, ue, ie, out);
}